// Round 2
// baseline (213.512 us; speedup 1.0000x reference)
//
#include <hip/hip_runtime.h>
#include <hip/hip_bf16.h>
#include <cstdint>

// Problem: out = softmax((x@Wq)(cond@Wkv[:, :64])^T / 8) @ (cond@Wkv[:, 64:])
// B=4, M=N=4096, DQ=256, H=64. fp32 in/out.
//
// Pipeline (all f16 MFMA, fp32 accum):
//  1) wtrans: W^T into f16 hi/lo pairs (q rows pre-scaled by log2e/8)
//  2) qproj / kvproj: MFMA projections (hi/lo split => ~fp32 accurate),
//     outputs q[BM][64], k[BN][64] f16 row-major, v transposed [B][64][N] f16
//  3) fa: flash attention, S^T orientation (one Q-row per lane), online softmax
//     in log2 domain, 2-way KV split => 512 blocks
//  4) merge: combine the two KV-split partials
//
// R1 fix: vt_lds staging covered only columns 0-63 (it<4, qq=cid&7) — upper
// half of each V^T tile was never written, PV used stale LDS. Now 8 iters,
// r=cid>>4, qq=cid&15 => full 64x128 tile staged.

#define BB 4
#define MM 4096
#define NN 4096
#define DQm 256
#define DH 64
#define QSCALE 0.18033688011112042f  // log2(e)/8

typedef _Float16 half8 __attribute__((ext_vector_type(8)));
typedef _Float16 half4 __attribute__((ext_vector_type(4)));
typedef float floatx16 __attribute__((ext_vector_type(16)));

// ---------------- W transpose + f16 hi/lo split -----------------------------
__global__ __launch_bounds__(256) void wtrans_kernel(const float* __restrict__ Wq,
                                                     const float* __restrict__ Wkv,
                                                     _Float16* __restrict__ wt) {
    int cout = blockIdx.x;   // 0..191 : 0-63 q (scaled), 64-127 k, 128-191 v
    int t = threadIdx.x;     // k index 0..255
    float v = (cout < 64) ? Wq[t * 64 + cout] * QSCALE : Wkv[t * 128 + (cout - 64)];
    _Float16 hi = (_Float16)v;
    _Float16 lo = (_Float16)(v - (float)hi);
    wt[cout * DQm + t] = hi;
    wt[192 * DQm + cout * DQm + t] = lo;
}

// ---------------- Q projection: 64 rows/block, C=64 -------------------------
__global__ __launch_bounds__(256) void qproj_kernel(const float* __restrict__ x,
                                                    const _Float16* __restrict__ wt,
                                                    _Float16* __restrict__ q_h) {
    __shared__ __align__(16) _Float16 xh[64][264];
    __shared__ __align__(16) _Float16 xl[64][264];
    const int t = threadIdx.x;
    const long row0 = (long)blockIdx.x * 64;
    const float4* xg = (const float4*)(x + row0 * DQm);
#pragma unroll
    for (int it = 0; it < 16; ++it) {
        int fid = t + it * 256;
        int row = fid >> 6, c4 = fid & 63;
        float4 v = xg[fid];
        half4 hh = {(_Float16)v.x, (_Float16)v.y, (_Float16)v.z, (_Float16)v.w};
        half4 hl = {(_Float16)(v.x - (float)hh[0]), (_Float16)(v.y - (float)hh[1]),
                    (_Float16)(v.z - (float)hh[2]), (_Float16)(v.w - (float)hh[3])};
        *(half4*)(&xh[row][c4 * 4]) = hh;
        *(half4*)(&xl[row][c4 * 4]) = hl;
    }
    __syncthreads();
    const int lane = t & 63, w = t >> 6, c = lane & 31, h = lane >> 5;
    const int rt = w & 1, ct = w >> 1;   // 2 row-tiles x 2 col-tiles
    const _Float16* wlo = wt + 192 * DQm;
    floatx16 acc;
#pragma unroll
    for (int i = 0; i < 16; ++i) acc[i] = 0.f;
#pragma unroll
    for (int kt = 0; kt < 16; ++kt) {
        half8 ah = *(const half8*)(&xh[rt * 32 + c][kt * 16 + h * 8]);
        half8 al = *(const half8*)(&xl[rt * 32 + c][kt * 16 + h * 8]);
        half8 bh = *(const half8*)(wt  + (long)(ct * 32 + c) * DQm + kt * 16 + h * 8);
        half8 bl = *(const half8*)(wlo + (long)(ct * 32 + c) * DQm + kt * 16 + h * 8);
        acc = __builtin_amdgcn_mfma_f32_32x32x16_f16(ah, bh, acc, 0, 0, 0);
        acc = __builtin_amdgcn_mfma_f32_32x32x16_f16(ah, bl, acc, 0, 0, 0);
        acc = __builtin_amdgcn_mfma_f32_32x32x16_f16(al, bh, acc, 0, 0, 0);
    }
#pragma unroll
    for (int r = 0; r < 16; ++r) {
        int m = (r & 3) + 8 * (r >> 2) + 4 * h;
        q_h[(row0 + rt * 32 + m) * DH + ct * 32 + c] = (_Float16)acc[r];
    }
}

// ---------------- KV projection: 64 rows/block, C=128 -----------------------
__global__ __launch_bounds__(256) void kvproj_kernel(const float* __restrict__ cond,
                                                     const _Float16* __restrict__ wt,
                                                     _Float16* __restrict__ k_h,
                                                     _Float16* __restrict__ vt_h) {
    __shared__ __align__(16) _Float16 xh[64][264];
    __shared__ __align__(16) _Float16 xl[64][264];
    const int t = threadIdx.x;
    const long row0 = (long)blockIdx.x * 64;
    const float4* xg = (const float4*)(cond + row0 * DQm);
#pragma unroll
    for (int it = 0; it < 16; ++it) {
        int fid = t + it * 256;
        int row = fid >> 6, c4 = fid & 63;
        float4 v = xg[fid];
        half4 hh = {(_Float16)v.x, (_Float16)v.y, (_Float16)v.z, (_Float16)v.w};
        half4 hl = {(_Float16)(v.x - (float)hh[0]), (_Float16)(v.y - (float)hh[1]),
                    (_Float16)(v.z - (float)hh[2]), (_Float16)(v.w - (float)hh[3])};
        *(half4*)(&xh[row][c4 * 4]) = hh;
        *(half4*)(&xl[row][c4 * 4]) = hl;
    }
    __syncthreads();
    const int lane = t & 63, w = t >> 6, c = lane & 31, h = lane >> 5;
    const int rt = w & 1, ctp = w >> 1;  // each wave: 1 row-tile x 2 col-tiles
    const _Float16* wlo = wt + 192 * DQm;
    floatx16 acc0, acc1;
#pragma unroll
    for (int i = 0; i < 16; ++i) { acc0[i] = 0.f; acc1[i] = 0.f; }
#pragma unroll
    for (int kt = 0; kt < 16; ++kt) {
        half8 ah = *(const half8*)(&xh[rt * 32 + c][kt * 16 + h * 8]);
        half8 al = *(const half8*)(&xl[rt * 32 + c][kt * 16 + h * 8]);
#pragma unroll
        for (int i = 0; i < 2; ++i) {
            long wrow = 64 + (ctp * 2 + i) * 32 + c;
            half8 bh = *(const half8*)(wt  + wrow * DQm + kt * 16 + h * 8);
            half8 bl = *(const half8*)(wlo + wrow * DQm + kt * 16 + h * 8);
            floatx16 a = i ? acc1 : acc0;
            a = __builtin_amdgcn_mfma_f32_32x32x16_f16(ah, bh, a, 0, 0, 0);
            a = __builtin_amdgcn_mfma_f32_32x32x16_f16(ah, bl, a, 0, 0, 0);
            a = __builtin_amdgcn_mfma_f32_32x32x16_f16(al, bh, a, 0, 0, 0);
            if (i) acc1 = a; else acc0 = a;
        }
    }
#pragma unroll
    for (int i = 0; i < 2; ++i) {
        const floatx16& acc = i ? acc1 : acc0;
        int cout = (ctp * 2 + i) * 32 + c;
        if (cout < 64) {
#pragma unroll
            for (int r = 0; r < 16; ++r) {
                int m = (r & 3) + 8 * (r >> 2) + 4 * h;
                k_h[(row0 + rt * 32 + m) * DH + cout] = (_Float16)acc[r];
            }
        } else {
            int d = cout - 64;
            long bb = row0 >> 12;  // batch (blocks never straddle)
#pragma unroll
            for (int s2 = 0; s2 < 4; ++s2) {
                long n = row0 + rt * 32 + 8 * s2 + 4 * h;
                half4 hv = {(_Float16)acc[s2 * 4 + 0], (_Float16)acc[s2 * 4 + 1],
                            (_Float16)acc[s2 * 4 + 2], (_Float16)acc[s2 * 4 + 3]};
                *(half4*)(vt_h + (bb * DH + d) * NN + (n & 4095)) = hv;
            }
        }
    }
}

// ---------------- Flash attention, S^T orientation --------------------------
// grid 512 = split(2) x b(4) x mtile(64). 128 threads = 2 waves x 32 Q rows.
__global__ __launch_bounds__(128) void fa_kernel(const _Float16* __restrict__ q_h,
                                                 const _Float16* __restrict__ k_h,
                                                 const _Float16* __restrict__ vt_h,
                                                 float* __restrict__ Opart,
                                                 float2* __restrict__ ml) {
    __shared__ __align__(16) _Float16 k_lds[128][72];    // [n][d], pad 8
    __shared__ __align__(16) _Float16 vt_lds[64][136];   // [d][n], pad 8
    __shared__ __align__(16) _Float16 p_lds[2][32][136]; // per wave [m][n], pad 8

    const int t = threadIdx.x;
    const int w = t >> 6;
    const int lane = t & 63;
    const int c = lane & 31;   // MFMA col index == this lane's Q row (local)
    const int h = lane >> 5;

    const int bid = blockIdx.x;
    const int sp = bid >> 8;          // KV split 0/1
    const int b  = (bid >> 6) & 3;
    const int mt = bid & 63;
    const int mbase = mt * 64 + w * 32;
    const long qrow = (long)b * MM + mbase + c;

    // Q as B-operand frags (held in regs all kernel): B[k=d][col=m]
    half8 qf[4];
#pragma unroll
    for (int kt = 0; kt < 4; ++kt)
        qf[kt] = *(const half8*)(q_h + qrow * DH + kt * 16 + h * 8);

    floatx16 Oc0, Oc1;   // O^T accum: rows d (2 tiles of 32), col m=c
#pragma unroll
    for (int i = 0; i < 16; ++i) { Oc0[i] = 0.f; Oc1[i] = 0.f; }
    float m_run = -INFINITY, l_run = 0.f;

#pragma unroll 1
    for (int nt = sp * 16; nt < sp * 16 + 16; ++nt) {
        const int n0 = nt * 128;
        __syncthreads();  // prior iter's LDS reads done before restage
        {
            const uint4* kg = (const uint4*)(k_h + ((long)b * NN + n0) * DH);
#pragma unroll
            for (int it = 0; it < 8; ++it) {
                int cid = t + it * 128;
                int r = cid >> 3, qq = cid & 7;
                *(uint4*)(&k_lds[r][qq * 8]) = kg[cid];
            }
#pragma unroll
            for (int it = 0; it < 8; ++it) {
                int cid = t + it * 128;
                int r = cid >> 4, qq = cid & 15;   // 64 rows x 16 chunks of 8
                *(uint4*)(&vt_lds[r][qq * 8]) =
                    *(const uint4*)(vt_h + ((long)b * DH + r) * NN + n0 + qq * 8);
            }
        }
        __syncthreads();

        // S^T = K * Q^T : 4 n-tiles of 32; D row = n-local, col = m = c
        floatx16 Sc[4];
#pragma unroll
        for (int ntile = 0; ntile < 4; ++ntile) {
            floatx16 acc;
#pragma unroll
            for (int i = 0; i < 16; ++i) acc[i] = 0.f;
#pragma unroll
            for (int kt = 0; kt < 4; ++kt) {
                half8 af = *(const half8*)(&k_lds[ntile * 32 + c][kt * 16 + h * 8]);
                acc = __builtin_amdgcn_mfma_f32_32x32x16_f16(af, qf[kt], acc, 0, 0, 0);
            }
            Sc[ntile] = acc;
        }

        // online softmax in log2 domain; every lane owns row m=c (n split over h)
        float tmax = -INFINITY;
#pragma unroll
        for (int n2 = 0; n2 < 4; ++n2)
#pragma unroll
            for (int r = 0; r < 16; ++r) tmax = fmaxf(tmax, Sc[n2][r]);
        tmax = fmaxf(tmax, __shfl_xor(tmax, 32));
        float m_new = fmaxf(m_run, tmax);
        float alpha = exp2f(m_run - m_new);
        float tsum = 0.f;
#pragma unroll
        for (int n2 = 0; n2 < 4; ++n2)
#pragma unroll
            for (int r = 0; r < 16; ++r) {
                float p = exp2f(Sc[n2][r] - m_new);
                Sc[n2][r] = p;
                tsum += p;
            }
        tsum += __shfl_xor(tsum, 32);
        l_run = l_run * alpha + tsum;
        m_run = m_new;
#pragma unroll
        for (int i = 0; i < 16; ++i) { Oc0[i] *= alpha; Oc1[i] *= alpha; }

        // P[m=c][n] to LDS: C-layout reg quads are 4 consecutive n -> b64 writes
#pragma unroll
        for (int n2 = 0; n2 < 4; ++n2)
#pragma unroll
            for (int s2 = 0; s2 < 4; ++s2) {
                half4 hv = {(_Float16)Sc[n2][s2 * 4 + 0], (_Float16)Sc[n2][s2 * 4 + 1],
                            (_Float16)Sc[n2][s2 * 4 + 2], (_Float16)Sc[n2][s2 * 4 + 3]};
                *(half4*)(&p_lds[w][c][n2 * 32 + s2 * 8 + h * 4]) = hv;
            }
        __asm__ volatile("s_waitcnt lgkmcnt(0)" ::: "memory");  // wave-local W->R

        // O^T += V^T * P^T : A=V^T (contiguous b128), B=P (contiguous b128)
#pragma unroll
        for (int kt = 0; kt < 8; ++kt) {
            half8 pf  = *(const half8*)(&p_lds[w][c][kt * 16 + h * 8]);
            half8 vf0 = *(const half8*)(&vt_lds[c][kt * 16 + h * 8]);
            half8 vf1 = *(const half8*)(&vt_lds[32 + c][kt * 16 + h * 8]);
            Oc0 = __builtin_amdgcn_mfma_f32_32x32x16_f16(vf0, pf, Oc0, 0, 0, 0);
            Oc1 = __builtin_amdgcn_mfma_f32_32x32x16_f16(vf1, pf, Oc1, 0, 0, 0);
        }
    }

    // epilogue: un-normalized partial + (m,l)
    const long obase = ((long)sp * BB * MM + (long)b * MM + mbase + c) * DH;
#pragma unroll
    for (int dt = 0; dt < 2; ++dt) {
        const floatx16& O = dt ? Oc1 : Oc0;
#pragma unroll
        for (int s2 = 0; s2 < 4; ++s2) {
            float4 v;
            v.x = O[s2 * 4 + 0]; v.y = O[s2 * 4 + 1];
            v.z = O[s2 * 4 + 2]; v.w = O[s2 * 4 + 3];
            *(float4*)(Opart + obase + dt * 32 + s2 * 8 + h * 4) = v;
        }
    }
    if (h == 0)
        ml[(long)sp * BB * MM + (long)b * MM + mbase + c] = make_float2(m_run, l_run);
}

// ---------------- merge the 2 KV-split partials ------------------------------
__global__ __launch_bounds__(256) void merge_kernel(const float* __restrict__ Opart,
                                                    const float2* __restrict__ ml,
                                                    float* __restrict__ out) {
    const long gid = (long)blockIdx.x * 256 + threadIdx.x;
    const long row = gid >> 6;
    const float2 p0 = ml[row];
    const float2 p1 = ml[(long)BB * MM + row];
    float mmax = fmaxf(p0.x, p1.x);
    float a0 = exp2f(p0.x - mmax), a1 = exp2f(p1.x - mmax);
    float denom = a0 * p0.y + a1 * p1.y;
    float o = a0 * Opart[gid] + a1 * Opart[(long)BB * MM * DH + gid];
    out[gid] = o / denom;
}

extern "C" void kernel_launch(void* const* d_in, const int* in_sizes, int n_in,
                              void* d_out, int out_size, void* d_ws, size_t ws_size,
                              hipStream_t stream) {
    const float* x    = (const float*)d_in[0];
    const float* cond = (const float*)d_in[1];
    const float* Wq   = (const float*)d_in[2];
    const float* Wkv  = (const float*)d_in[3];
    float* out = (float*)d_out;

    char* ws = (char*)d_ws;
    // ws layout (bytes): wt hi+lo 2*192*256*2 = 196608; q 2MB; k 2MB; vt 2MB;
    // Opart 2*4MB; ml 2*16384*8 = 256KB  -> ~14.6MB total
    _Float16* wt   = (_Float16*)(ws);
    _Float16* q_h  = (_Float16*)(ws + 196608);
    _Float16* k_h  = (_Float16*)(ws + 196608 + 2097152);
    _Float16* vt_h = (_Float16*)(ws + 196608 + 2 * 2097152);
    float*    Op   = (float*)(ws + 196608 + 3 * 2097152);
    float2*   mlp  = (float2*)(ws + 196608 + 3 * 2097152 + 8388608);

    wtrans_kernel<<<192, 256, 0, stream>>>(Wq, Wkv, wt);
    qproj_kernel<<<BB * MM / 64, 256, 0, stream>>>(x, wt, q_h);
    kvproj_kernel<<<BB * NN / 64, 256, 0, stream>>>(cond, wt, k_h, vt_h);
    fa_kernel<<<512, 128, 0, stream>>>(q_h, k_h, vt_h, Op, mlp);
    merge_kernel<<<BB * MM * DH / 256, 256, 0, stream>>>(Op, mlp, out);
}

// Round 4
// 137.851 us; speedup vs baseline: 1.5489x; 1.5489x over previous
//
#include <hip/hip_runtime.h>
#include <hip/hip_bf16.h>
#include <cstdint>

// out = softmax((x@Wq)(cond@Wkv[:,:64])^T / 8) @ (cond@Wkv[:,64:])
// B=4, M=N=4096, DQ=256, H=64. fp32 in/out.
//
// R2 restructure (R1 was latency-bound: 1 wave/SIMD, MfmaUtil 5.5%):
//  - fa: 256 thr (4 waves x 32 Q rows), KV tile 64, 4-way KV split
//    -> 2048 waves (8/CU). p_lds removed: P goes C-layout -> B-operand
//    layout via v_cvt_pkrtz + one shfl_xor(32) per quad pair (in-register
//    transpose). LDS 52.8KB -> 18.4KB.
//  - qproj/kvproj: 3 independent MFMA accumulator chains per output tile
//    (was one 48-deep serial chain).
// R3: fix pkrtz union type (__builtin_amdgcn_cvt_pkrtz returns __fp16x2).

#define BB 4
#define MM 4096
#define NN 4096
#define DQm 256
#define DH 64
#define NSP 4                        // KV splits
#define QSCALE 0.18033688011112042f  // log2(e)/8

typedef _Float16 half8 __attribute__((ext_vector_type(8)));
typedef _Float16 half4 __attribute__((ext_vector_type(4)));
typedef float floatx16 __attribute__((ext_vector_type(16)));

static __device__ __forceinline__ unsigned pkrtz(float a, float b) {
    union { __fp16 h __attribute__((ext_vector_type(2))); unsigned u; } cv;
    cv.h = __builtin_amdgcn_cvt_pkrtz(a, b);
    return cv.u;
}

// ---------------- W transpose + f16 hi/lo split -----------------------------
__global__ __launch_bounds__(256) void wtrans_kernel(const float* __restrict__ Wq,
                                                     const float* __restrict__ Wkv,
                                                     _Float16* __restrict__ wt) {
    int cout = blockIdx.x;   // 0..191 : 0-63 q (scaled), 64-127 k, 128-191 v
    int t = threadIdx.x;     // k index 0..255
    float v = (cout < 64) ? Wq[t * 64 + cout] * QSCALE : Wkv[t * 128 + (cout - 64)];
    _Float16 hi = (_Float16)v;
    _Float16 lo = (_Float16)(v - (float)hi);
    wt[cout * DQm + t] = hi;
    wt[192 * DQm + cout * DQm + t] = lo;
}

// ---------------- Q projection: 64 rows/block, C=64 -------------------------
__global__ __launch_bounds__(256) void qproj_kernel(const float* __restrict__ x,
                                                    const _Float16* __restrict__ wt,
                                                    _Float16* __restrict__ q_h) {
    __shared__ __align__(16) _Float16 xh[64][264];
    __shared__ __align__(16) _Float16 xl[64][264];
    const int t = threadIdx.x;
    const long row0 = (long)blockIdx.x * 64;
    const float4* xg = (const float4*)(x + row0 * DQm);
#pragma unroll
    for (int it = 0; it < 16; ++it) {
        int fid = t + it * 256;
        int row = fid >> 6, c4 = fid & 63;
        float4 v = xg[fid];
        half4 hh = {(_Float16)v.x, (_Float16)v.y, (_Float16)v.z, (_Float16)v.w};
        half4 hl = {(_Float16)(v.x - (float)hh[0]), (_Float16)(v.y - (float)hh[1]),
                    (_Float16)(v.z - (float)hh[2]), (_Float16)(v.w - (float)hh[3])};
        *(half4*)(&xh[row][c4 * 4]) = hh;
        *(half4*)(&xl[row][c4 * 4]) = hl;
    }
    __syncthreads();
    const int lane = t & 63, w = t >> 6, c = lane & 31, h = lane >> 5;
    const int rt = w & 1, ct = w >> 1;   // 2 row-tiles x 2 col-tiles
    const _Float16* wlo = wt + 192 * DQm;
    floatx16 a1, a2, a3;   // 3 independent chains: ah*bh, ah*bl, al*bh
#pragma unroll
    for (int i = 0; i < 16; ++i) { a1[i] = 0.f; a2[i] = 0.f; a3[i] = 0.f; }
#pragma unroll
    for (int kt = 0; kt < 16; ++kt) {
        half8 ah = *(const half8*)(&xh[rt * 32 + c][kt * 16 + h * 8]);
        half8 al = *(const half8*)(&xl[rt * 32 + c][kt * 16 + h * 8]);
        half8 bh = *(const half8*)(wt  + (long)(ct * 32 + c) * DQm + kt * 16 + h * 8);
        half8 bl = *(const half8*)(wlo + (long)(ct * 32 + c) * DQm + kt * 16 + h * 8);
        a1 = __builtin_amdgcn_mfma_f32_32x32x16_f16(ah, bh, a1, 0, 0, 0);
        a2 = __builtin_amdgcn_mfma_f32_32x32x16_f16(ah, bl, a2, 0, 0, 0);
        a3 = __builtin_amdgcn_mfma_f32_32x32x16_f16(al, bh, a3, 0, 0, 0);
    }
#pragma unroll
    for (int r = 0; r < 16; ++r) {
        int m = (r & 3) + 8 * (r >> 2) + 4 * h;
        q_h[(row0 + rt * 32 + m) * DH + ct * 32 + c] = (_Float16)(a1[r] + a2[r] + a3[r]);
    }
}

// ---------------- KV projection: 64 rows/block, C=128 -----------------------
__global__ __launch_bounds__(256) void kvproj_kernel(const float* __restrict__ cond,
                                                     const _Float16* __restrict__ wt,
                                                     _Float16* __restrict__ k_h,
                                                     _Float16* __restrict__ vt_h) {
    __shared__ __align__(16) _Float16 xh[64][264];
    __shared__ __align__(16) _Float16 xl[64][264];
    const int t = threadIdx.x;
    const long row0 = (long)blockIdx.x * 64;
    const float4* xg = (const float4*)(cond + row0 * DQm);
#pragma unroll
    for (int it = 0; it < 16; ++it) {
        int fid = t + it * 256;
        int row = fid >> 6, c4 = fid & 63;
        float4 v = xg[fid];
        half4 hh = {(_Float16)v.x, (_Float16)v.y, (_Float16)v.z, (_Float16)v.w};
        half4 hl = {(_Float16)(v.x - (float)hh[0]), (_Float16)(v.y - (float)hh[1]),
                    (_Float16)(v.z - (float)hh[2]), (_Float16)(v.w - (float)hh[3])};
        *(half4*)(&xh[row][c4 * 4]) = hh;
        *(half4*)(&xl[row][c4 * 4]) = hl;
    }
    __syncthreads();
    const int lane = t & 63, w = t >> 6, c = lane & 31, h = lane >> 5;
    const int rt = w & 1, ctp = w >> 1;  // each wave: 1 row-tile x 2 col-tiles
    const _Float16* wlo = wt + 192 * DQm;
    floatx16 a1[2], a2[2], a3[2];        // 3 chains x 2 col-tiles
#pragma unroll
    for (int i = 0; i < 16; ++i) {
        a1[0][i] = 0.f; a2[0][i] = 0.f; a3[0][i] = 0.f;
        a1[1][i] = 0.f; a2[1][i] = 0.f; a3[1][i] = 0.f;
    }
#pragma unroll
    for (int kt = 0; kt < 16; ++kt) {
        half8 ah = *(const half8*)(&xh[rt * 32 + c][kt * 16 + h * 8]);
        half8 al = *(const half8*)(&xl[rt * 32 + c][kt * 16 + h * 8]);
#pragma unroll
        for (int i = 0; i < 2; ++i) {
            long wrow = 64 + (ctp * 2 + i) * 32 + c;
            half8 bh = *(const half8*)(wt  + wrow * DQm + kt * 16 + h * 8);
            half8 bl = *(const half8*)(wlo + wrow * DQm + kt * 16 + h * 8);
            a1[i] = __builtin_amdgcn_mfma_f32_32x32x16_f16(ah, bh, a1[i], 0, 0, 0);
            a2[i] = __builtin_amdgcn_mfma_f32_32x32x16_f16(ah, bl, a2[i], 0, 0, 0);
            a3[i] = __builtin_amdgcn_mfma_f32_32x32x16_f16(al, bh, a3[i], 0, 0, 0);
        }
    }
#pragma unroll
    for (int i = 0; i < 2; ++i) {
        int cout = (ctp * 2 + i) * 32 + c;
        if (cout < 64) {
#pragma unroll
            for (int r = 0; r < 16; ++r) {
                int m = (r & 3) + 8 * (r >> 2) + 4 * h;
                k_h[(row0 + rt * 32 + m) * DH + cout] =
                    (_Float16)(a1[i][r] + a2[i][r] + a3[i][r]);
            }
        } else {
            int d = cout - 64;
            long bb = row0 >> 12;  // batch (blocks never straddle)
#pragma unroll
            for (int s2 = 0; s2 < 4; ++s2) {
                long n = row0 + rt * 32 + 8 * s2 + 4 * h;
                half4 hv;
#pragma unroll
                for (int j = 0; j < 4; ++j)
                    hv[j] = (_Float16)(a1[i][s2 * 4 + j] + a2[i][s2 * 4 + j] +
                                       a3[i][s2 * 4 + j]);
                *(half4*)(vt_h + (bb * DH + d) * NN + (n & 4095)) = hv;
            }
        }
    }
}

// ---------------- Flash attention ------------------------------------------
// grid 512 = sp(4) x b(4) x mtile(32). 256 thr = 4 waves x 32 Q rows.
// KV tile 64. P never touches LDS: in-register C->B layout transform.
__global__ __launch_bounds__(256, 2) void fa_kernel(const _Float16* __restrict__ q_h,
                                                    const _Float16* __restrict__ k_h,
                                                    const _Float16* __restrict__ vt_h,
                                                    float* __restrict__ Opart,
                                                    float2* __restrict__ ml) {
    __shared__ __align__(16) _Float16 k_lds[64][72];   // [n][d], pad 8
    __shared__ __align__(16) _Float16 vt_lds[64][72];  // [d][n], pad 8

    const int t = threadIdx.x;
    const int w = t >> 6;
    const int lane = t & 63;
    const int c = lane & 31;   // MFMA col == this lane's Q row (local)
    const int h = lane >> 5;

    const int bid = blockIdx.x;
    const int sp = bid >> 7;          // KV split 0..3
    const int b  = (bid >> 5) & 3;
    const int mt = bid & 31;
    const int mbase = mt * 128 + w * 32;
    const long qrow = (long)b * MM + mbase + c;

    // Q as B-operand frags (regs all kernel): B[k=d][col=m]
    half8 qf[4];
#pragma unroll
    for (int kt = 0; kt < 4; ++kt)
        qf[kt] = *(const half8*)(q_h + qrow * DH + kt * 16 + h * 8);

    floatx16 Oc0, Oc1;   // O^T accum: d rows (2 tiles of 32), col m=c
#pragma unroll
    for (int i = 0; i < 16; ++i) { Oc0[i] = 0.f; Oc1[i] = 0.f; }
    float m_run = -INFINITY, l_run = 0.f;

#pragma unroll 1
    for (int nt = sp * 16; nt < sp * 16 + 16; ++nt) {
        const int n0 = nt * 64;
        __syncthreads();  // prior iter's LDS reads done before restage
        {
            const uint4* kg = (const uint4*)(k_h + ((long)b * NN + n0) * DH);
#pragma unroll
            for (int it = 0; it < 2; ++it) {
                int cid = t + it * 256;            // 0..511
                int r = cid >> 3, q = cid & 7;
                *(uint4*)(&k_lds[r][q * 8]) = kg[cid];
                *(uint4*)(&vt_lds[r][q * 8]) =
                    *(const uint4*)(vt_h + ((long)b * DH + r) * NN + n0 + q * 8);
            }
        }
        __syncthreads();

        // S^T = K * Q^T : 2 n-tiles of 32; D row = n-local, col = m = c
        floatx16 Sc[2];
#pragma unroll
        for (int a = 0; a < 2; ++a) {
            floatx16 acc;
#pragma unroll
            for (int i = 0; i < 16; ++i) acc[i] = 0.f;
#pragma unroll
            for (int kt = 0; kt < 4; ++kt) {
                half8 af = *(const half8*)(&k_lds[a * 32 + c][kt * 16 + h * 8]);
                acc = __builtin_amdgcn_mfma_f32_32x32x16_f16(af, qf[kt], acc, 0, 0, 0);
            }
            Sc[a] = acc;
        }

        // online softmax (log2 domain); lane owns row m=c, n split across h
        float tmax = -INFINITY;
#pragma unroll
        for (int a = 0; a < 2; ++a)
#pragma unroll
            for (int r = 0; r < 16; ++r) tmax = fmaxf(tmax, Sc[a][r]);
        tmax = fmaxf(tmax, __shfl_xor(tmax, 32, 64));
        float m_new = fmaxf(m_run, tmax);
        float alpha = exp2f(m_run - m_new);
        float tsum = 0.f;
#pragma unroll
        for (int a = 0; a < 2; ++a)
#pragma unroll
            for (int r = 0; r < 16; ++r) {
                float p = exp2f(Sc[a][r] - m_new);
                Sc[a][r] = p;
                tsum += p;
            }
        tsum += __shfl_xor(tsum, 32, 64);
        l_run = l_run * alpha + tsum;
        m_run = m_new;
#pragma unroll
        for (int i = 0; i < 16; ++i) { Oc0[i] *= alpha; Oc1[i] *= alpha; }

        // P: C-layout -> B-operand frags, in-register.
        // quad q of tile a = Sc[a][4q..4q+3] = rows 8q+4h..+3 of S^T tile.
        // frag[kt=2a+b] = j0-3: quad(2b+h) of (c,0); j4-7: quad(2b+h) of (c,1)
#pragma unroll
        for (int a = 0; a < 2; ++a) {
            uint2 pk0 = {pkrtz(Sc[a][0],  Sc[a][1]),  pkrtz(Sc[a][2],  Sc[a][3])};
            uint2 pk1 = {pkrtz(Sc[a][4],  Sc[a][5]),  pkrtz(Sc[a][6],  Sc[a][7])};
            uint2 pk2 = {pkrtz(Sc[a][8],  Sc[a][9]),  pkrtz(Sc[a][10], Sc[a][11])};
            uint2 pk3 = {pkrtz(Sc[a][12], Sc[a][13]), pkrtz(Sc[a][14], Sc[a][15])};
            uint2 s0, s1, ex0, ex1;
            s0.x = h ? pk0.x : pk1.x;  s0.y = h ? pk0.y : pk1.y;  // send quad 2*0+(h^1)
            s1.x = h ? pk2.x : pk3.x;  s1.y = h ? pk2.y : pk3.y;  // send quad 2*1+(h^1)
            ex0.x = __shfl_xor((int)s0.x, 32, 64);  // recv partner quad 0+h
            ex0.y = __shfl_xor((int)s0.y, 32, 64);
            ex1.x = __shfl_xor((int)s1.x, 32, 64);  // recv partner quad 2+h
            ex1.y = __shfl_xor((int)s1.y, 32, 64);
            union { uint4 u; half8 f; } f0, f1;
            f0.u.x = h ? ex0.x : pk0.x;  f0.u.y = h ? ex0.y : pk0.y;
            f0.u.z = h ? pk1.x : ex0.x;  f0.u.w = h ? pk1.y : ex0.y;
            f1.u.x = h ? ex1.x : pk2.x;  f1.u.y = h ? ex1.y : pk2.y;
            f1.u.z = h ? pk3.x : ex1.x;  f1.u.w = h ? pk3.y : ex1.y;
            // O^T += V^T * P^T for kt = 2a, 2a+1
#pragma unroll
            for (int bq = 0; bq < 2; ++bq) {
                int kt = 2 * a + bq;
                half8 pf = bq ? f1.f : f0.f;
                half8 vf0 = *(const half8*)(&vt_lds[c][kt * 16 + h * 8]);
                half8 vf1 = *(const half8*)(&vt_lds[32 + c][kt * 16 + h * 8]);
                Oc0 = __builtin_amdgcn_mfma_f32_32x32x16_f16(vf0, pf, Oc0, 0, 0, 0);
                Oc1 = __builtin_amdgcn_mfma_f32_32x32x16_f16(vf1, pf, Oc1, 0, 0, 0);
            }
        }
    }

    // epilogue: un-normalized partial + (m,l)
    const long obase = ((long)sp * BB * MM + (long)b * MM + mbase + c) * DH;
#pragma unroll
    for (int dt = 0; dt < 2; ++dt) {
        const floatx16& O = dt ? Oc1 : Oc0;
#pragma unroll
        for (int s2 = 0; s2 < 4; ++s2) {
            float4 v;
            v.x = O[s2 * 4 + 0]; v.y = O[s2 * 4 + 1];
            v.z = O[s2 * 4 + 2]; v.w = O[s2 * 4 + 3];
            *(float4*)(Opart + obase + dt * 32 + s2 * 8 + h * 4) = v;
        }
    }
    if (h == 0)
        ml[((long)sp * BB + b) * MM + mbase + c] = make_float2(m_run, l_run);
}

// ---------------- merge the NSP KV-split partials ----------------------------
__global__ __launch_bounds__(256) void merge_kernel(const float* __restrict__ Opart,
                                                    const float2* __restrict__ ml,
                                                    float* __restrict__ out) {
    const long gid = (long)blockIdx.x * 256 + threadIdx.x;
    const long row = gid >> 6;
    float2 p[NSP];
    float mmax = -INFINITY;
#pragma unroll
    for (int i = 0; i < NSP; ++i) {
        p[i] = ml[(long)i * BB * MM + row];
        mmax = fmaxf(mmax, p[i].x);
    }
    float denom = 0.f, o = 0.f;
#pragma unroll
    for (int i = 0; i < NSP; ++i) {
        float ai = exp2f(p[i].x - mmax);
        denom += ai * p[i].y;
        o += ai * Opart[(long)i * BB * MM * DH + gid];
    }
    out[gid] = o / denom;
}

extern "C" void kernel_launch(void* const* d_in, const int* in_sizes, int n_in,
                              void* d_out, int out_size, void* d_ws, size_t ws_size,
                              hipStream_t stream) {
    const float* x    = (const float*)d_in[0];
    const float* cond = (const float*)d_in[1];
    const float* Wq   = (const float*)d_in[2];
    const float* Wkv  = (const float*)d_in[3];
    float* out = (float*)d_out;

    char* ws = (char*)d_ws;
    // ws: wt 196608 | q 2MB | k 2MB | vt 2MB | Opart 4x4MB | ml 512KB  ~22.7MB
    _Float16* wt   = (_Float16*)(ws);
    _Float16* q_h  = (_Float16*)(ws + 196608);
    _Float16* k_h  = (_Float16*)(ws + 196608 + 2097152);
    _Float16* vt_h = (_Float16*)(ws + 196608 + 2 * 2097152);
    float*    Op   = (float*)(ws + 196608 + 3 * 2097152);
    float2*   mlp  = (float2*)(ws + 196608 + 3 * 2097152 + (size_t)NSP * 4194304);

    wtrans_kernel<<<192, 256, 0, stream>>>(Wq, Wkv, wt);
    qproj_kernel<<<BB * MM / 64, 256, 0, stream>>>(x, wt, q_h);
    kvproj_kernel<<<BB * NN / 64, 256, 0, stream>>>(cond, wt, k_h, vt_h);
    fa_kernel<<<NSP * BB * 32, 256, 0, stream>>>(q_h, k_h, vt_h, Op, mlp);
    merge_kernel<<<BB * MM * DH / 256, 256, 0, stream>>>(Op, mlp, out);
}